// Round 7
// baseline (419.121 us; speedup 1.0000x reference)
//
#include <hip/hip_runtime.h>
#include <hip/hip_bf16.h>

// ---------------------------------------------------------------------------
// GAT forward: 3 layers, N=100k nodes, D=64, E=1.6M edges (+N self loops).
// R16: direct CSR build via global atomics (pairs/bucket machinery deleted):
//   memset(deg,rank) -> conv_deg_k (conversions + atomic degree count)
//   -> scan1_k/scan2_k (rowptr, +1 self loop per node)
//   -> scat_gemm_k (direct col scatter via atomic rank + self loops
//      + layer-0 gemm strips riding along)
// Compute: aggemm_k (layers 0,1: R11 agg body + fused next-layer gemm,
// x_lds padded [16][72]), agg_k (final layer, R11 verbatim + 4-layer mean).
// Row contract unchanged: neighbors (arbitrary order), self-loop last.
// Within-row order was already nondeterministic (atomic arrival) in R13-R15.
// ---------------------------------------------------------------------------

#define BSHIFT 9
#define NPB 512            // nodes per scan block
#define FRAG_STRIDE 5120   // 10 frags * 64 lanes * 8 halves per layer
#define DCHUNK 2048        // edges per scatter/count chunk

typedef _Float16 v8h __attribute__((ext_vector_type(8)));
typedef float v4f __attribute__((ext_vector_type(4)));
typedef unsigned short u16x8 __attribute__((ext_vector_type(8)));

__device__ inline float bf2f(unsigned short u) {
    return __uint_as_float(((unsigned int)u) << 16);
}
__device__ inline unsigned short f2bf(float v) {
    __hip_bfloat16 b = __float2bfloat16(v);
    return *reinterpret_cast<unsigned short*>(&b);
}
__device__ inline unsigned short f2h_u(float v) {
    return __builtin_bit_cast(unsigned short, (_Float16)v);
}
__device__ inline float h2f_u(unsigned short u) {
    return (float)__builtin_bit_cast(_Float16, u);
}

__device__ __forceinline__ void fma8(float* acc, float al, const u16x8& hv) {
    #pragma unroll
    for (int i = 0; i < 8; ++i) acc[i] = fmaf(al, h2f_u(hv[i]), acc[i]);
}

__device__ inline float load_in(const void* p, int i, int isbf) {
    if (isbf) return bf2f(((const unsigned short*)p)[i]);
    return ((const float*)p)[i];
}

// per-block dtype detection: all blocks sample the same first 1KB of emb ->
// deterministic identical answer (bf16 ~97% exponent-byte hits, f32 ~4%).
__device__ inline int detect_bf16_blk(const unsigned int* raw) {
    __shared__ int s4[4];
    unsigned int b = (raw[threadIdx.x] >> 8) & 0x7Fu;
    unsigned long long m = __ballot(b >= 0x3Bu && b <= 0x3Fu);
    int wv = threadIdx.x >> 6;
    if ((threadIdx.x & 63) == 0) s4[wv] = __popcll(m);
    __syncthreads();
    return (s4[0] + s4[1] + s4[2] + s4[3]) > 128 ? 1 : 0;
}

// blocks [0, dchunk): per-edge degree count via global atomics (deg pre-zeroed)
// blocks [dchunk, ...): conversions (emb->x0 fp16, W->frags, bias), flag store
__global__ __launch_bounds__(256) void conv_deg_k(const void* emb, const void* W, const void* as_,
                                                  const void* ad_, const void* b_,
                                                  const int* __restrict__ dst,
                                                  unsigned short* x0, unsigned short* Whf,
                                                  float* bf, int* __restrict__ deg, int* flag,
                                                  int n, int L_, int E, int dchunk) {
    int blk = blockIdx.x;
    if (blk < dchunk) {
        int cs = blk * DCHUNK;
        int ce = min(cs + DCHUNK, E);
        for (int i = cs + threadIdx.x; i < ce; i += 256)
            atomicAdd(&deg[dst[i]], 1);
        return;
    }
    int isbf = detect_bf16_blk((const unsigned int*)emb);
    int i = (blk - dchunk) * 256 + threadIdx.x;
    if (blk == dchunk && threadIdx.x == 0) *flag = isbf;
    // vectorized emb -> x0 fp16 conversion: 8 elems / thread (n % 8 == 0)
    long i8 = (long)i * 8;
    if (i8 < n) {
        u16x8 o;
        if (isbf) {
            u16x8 v = *(const u16x8*)((const unsigned short*)emb + i8);
            #pragma unroll
            for (int q = 0; q < 8; ++q) o[q] = f2h_u(bf2f(v[q]));
        } else {
            v4f f0 = *(const v4f*)((const float*)emb + i8);
            v4f f1 = *(const v4f*)((const float*)emb + i8 + 4);
            #pragma unroll
            for (int q = 0; q < 4; ++q) { o[q] = f2h_u(f0[q]); o[q + 4] = f2h_u(f1[q]); }
        }
        *(u16x8*)(x0 + i8) = o;
    }
    if (i < L_ * 4096) {
        int l = i >> 12, rem = i & 4095;
        int k = rem >> 6, c64 = rem & 63;
        int t = c64 >> 4, c = c64 & 15;
        int kf = k >> 5, quad = (k >> 3) & 3, j = k & 7;
        int f = t * 2 + kf, lane = quad * 16 + c;
        Whf[l * FRAG_STRIDE + (f * 64 + lane) * 8 + j] = f2h_u(load_in(W, i, isbf));
    }
    if (i < L_ * 1024) {                 // score tile: frags 8 (k<32), 9 (k>=32)
        int l = i >> 10, r = i & 1023;
        int kf = r >> 9, rr = r & 511;
        int lane = rr >> 3, j = rr & 7;
        int c = lane & 15, quad = lane >> 4;
        int k = kf * 32 + quad * 8 + j;
        float val = 0.f;
        if (c < 2) {
            const void* av = c ? ad_ : as_;
            float dot = 0.f;
            for (int cc = 0; cc < 64; ++cc)
                dot += load_in(W, l * 4096 + k * 64 + cc, isbf) * load_in(av, l * 64 + cc, isbf);
            val = dot;                   // (W @ a)[k]
        }
        Whf[l * FRAG_STRIDE + ((8 + kf) * 64 + lane) * 8 + j] = f2h_u(val);
    }
    if (i < L_ * 64) bf[i] = load_in(b_, i, isbf);
}

// ---- rowptr build ----------------------------------------------------------

// block b: bsum[b] = sum of deg over nodes [b*512, b*512+512)
__global__ __launch_bounds__(256) void scan1_k(const int* __restrict__ deg,
                                               int* __restrict__ bsum, int N) {
    __shared__ int s[256];
    int b = blockIdx.x, t = threadIdx.x;
    int i0 = (b << BSHIFT) + 2 * t, i1 = i0 + 1;
    int v = ((i0 < N) ? deg[i0] : 0) + ((i1 < N) ? deg[i1] : 0);
    s[t] = v;
    __syncthreads();
    for (int o = 128; o; o >>= 1) {
        if (t < o) s[t] += s[t + o];
        __syncthreads();
    }
    if (t == 0) bsum[b] = s[0];
}

// block b: base = exclusive prefix over (bsum[k] + nloc_k); then local
// exclusive scan of (deg+1) over the block's 512 nodes -> rowptr.
__global__ __launch_bounds__(512) void scan2_k(const int* __restrict__ deg,
                                               const int* __restrict__ bsum,
                                               int* __restrict__ rowptr,
                                               int N, int E, int NB) {
    __shared__ int s2[256];
    __shared__ int sc[512];
    int b = blockIdx.x, t = threadIdx.x;
    if (t < 256) {
        int hv = (t < NB) ? bsum[t] + min(N - (t << BSHIFT), NPB) : 0;
        s2[t] = hv;
    }
    __syncthreads();
    for (int o = 1; o < 256; o <<= 1) {
        int tv = (t >= o && t < 256) ? s2[t - o] : 0;
        __syncthreads();
        if (t < 256) s2[t] += tv;
        __syncthreads();
    }
    int base = (b > 0) ? s2[b - 1] : 0;

    int node = (b << BSHIFT) + t;
    int nloc = min(N - (b << BSHIFT), NPB);
    int v = (t < nloc) ? deg[node] + 1 : 0;      // +1 self loop
    sc[t] = v;
    __syncthreads();
    for (int o = 1; o < 512; o <<= 1) {
        int tv = (t >= o) ? sc[t - o] : 0;
        __syncthreads();
        sc[t] += tv;
        __syncthreads();
    }
    int excl = sc[t] - v;
    if (t < nloc) rowptr[node] = base + excl;
    if (b == 0 && t == 0) rowptr[N] = E + N;
}

// blocks [0, schunk): direct scatter col[rowptr[d] + rank[d]++] = src
// blocks [schunk, +selfb): self-loop in last slot col[rowptr[i]+deg[i]] = i
// blocks [rest): layer-0 gemm strips (independent -> overlap the scatter)
__global__ __launch_bounds__(256) void scat_gemm_k(const int* __restrict__ src,
                                                   const int* __restrict__ dst,
                                                   const int* __restrict__ rowptr,
                                                   const int* __restrict__ deg,
                                                   int* __restrict__ rank,
                                                   int* __restrict__ col,
                                                   int E, int N, int schunk, int selfb,
                                                   const unsigned short* __restrict__ x,
                                                   const unsigned short* __restrict__ Whf,
                                                   unsigned short* __restrict__ h,
                                                   float* __restrict__ es, float* __restrict__ ed,
                                                   int nblk) {
    int t = threadIdx.x;
    int blk = blockIdx.x;

    if (blk < schunk) {
        int cs = blk * DCHUNK;
        int ce = min(cs + DCHUNK, E);
        for (int i = cs + t; i < ce; i += 256) {
            int d = dst[i];
            int r = atomicAdd(&rank[d], 1);
            col[rowptr[d] + r] = src[i];
        }
        return;
    }
    blk -= schunk;
    if (blk < selfb) {
        int i = blk * 256 + t;
        if (i < N) col[rowptr[i] + deg[i]] = i;   // self-loop: last slot
        return;
    }
    blk -= selfb;

    // ---- layer-0 gemm strip (one 16-node strip per wave) ----
    int lane = t & 63;
    int gw = (blk << 2) + (t >> 6);
    if (gw >= nblk) return;
    int c = lane & 15, quad = lane >> 4;
    v8h bfr[10];
    #pragma unroll
    for (int f = 0; f < 10; ++f)
        bfr[f] = *(const v8h*)(Whf + (size_t)(f * 64 + lane) * 8);
    v4f z = {0.f, 0.f, 0.f, 0.f};
    int base = gw * 16;
    int m = base + c; if (m >= N) m = N - 1;
    const v8h a0 = *(const v8h*)(x + (size_t)m * 64 + quad * 8);
    const v8h a1 = *(const v8h*)(x + (size_t)m * 64 + 32 + quad * 8);
    v4f acc[5];
    #pragma unroll
    for (int tt = 0; tt < 5; ++tt) {
        acc[tt] = __builtin_amdgcn_mfma_f32_16x16x32_f16(a0, bfr[2 * tt], z, 0, 0, 0);
        acc[tt] = __builtin_amdgcn_mfma_f32_16x16x32_f16(a1, bfr[2 * tt + 1], acc[tt], 0, 0, 0);
    }
    #pragma unroll
    for (int r = 0; r < 4; ++r) {
        int row = base + quad * 4 + r;
        if (row < N) {
            #pragma unroll
            for (int tt = 0; tt < 4; ++tt)
                h[(size_t)row * 64 + tt * 16 + c] = f2h_u(acc[tt][r]);
            if (c == 0) es[row] = acc[4][r];
            if (c == 1) ed[row] = acc[4][r];
        }
    }
}

// ---- per-layer compute -----------------------------------------------------

__device__ inline float elu_f(float v) { return v > 0.f ? v : (__expf(v) - 1.f); }

// Fused agg + next-layer gemm. Block = 8 waves = 16 nodes = 1 gemm strip.
// Agg body is R11 verbatim. Output x rows stashed in LDS (padded [16][72] to
// break the MFMA-read bank conflict); after the block barrier, waves 0-4
// each compute one 16x16 col-tile of the NEXT layer's h / es,ed via the same
// MFMA sequence gemm uses -> bit-identical h/es/ed.
__global__ __launch_bounds__(512) void aggemm_k(const unsigned short* __restrict__ h,
                                                const float* __restrict__ es,
                                                const float* __restrict__ ed,
                                                const int* __restrict__ rowptr,
                                                const int* __restrict__ col,
                                                const float* __restrict__ bias,
                                                unsigned short* __restrict__ xo,
                                                const unsigned short* __restrict__ Whf2,
                                                unsigned short* __restrict__ h2,
                                                float* __restrict__ es2,
                                                float* __restrict__ ed2,
                                                int n) {
    __shared__ unsigned short x_lds[16][72];   // padded: 144B row stride
    int wvl = threadIdx.x >> 6;          // 0..7
    int lane = threadIdx.x & 63;
    int blk16 = blockIdx.x * 16;
    int n0 = blk16 + wvl * 2;

    if (n0 < n) {
        int half = lane >> 5, hl = lane & 31;
        int node = n0 + half;
        bool valid = node < n;
        int nodeC = valid ? node : n - 1;
        int r0 = rowptr[nodeC];
        int deg = valid ? (rowptr[nodeC + 1] - r0) : 0;

        if (__ballot(deg > 32) == 0) {
            float edd = valid ? ed[nodeC] : 0.f;
            bool has = hl < deg;
            int c = 0;
            float esv = 0.f;
            if (has) {
                c = col[r0 + hl];
                esv = es[(unsigned)c];
            }

            int deg0 = __shfl(deg, 0), deg1 = __shfl(deg, 32);
            int g = lane >> 3, j = lane & 7;
            unsigned joff = (unsigned)j * 8;
            int i0 = g, i1 = 8 + g, i2 = 16 + g, i3 = 24 + g;

            int s00 = __shfl(c, i0), s01 = __shfl(c, i1);
            int s10 = __shfl(c, 32 + i0), s11 = __shfl(c, 32 + i1);
            int s02 = __shfl(c, i2), s03 = __shfl(c, i3);
            int s12 = __shfl(c, 32 + i2), s13 = __shfl(c, 32 + i3);
            bool p00 = i0 < deg0, p01 = i1 < deg0, p02 = i2 < deg0, p03 = i3 < deg0;
            bool p10 = i0 < deg1, p11 = i1 < deg1, p12 = i2 < deg1, p13 = i3 < deg1;
            u16x8 h00, h01, h10, h11, h02, h03, h12, h13;
            if (p00) h00 = *(const u16x8*)(h + ((unsigned)s00 * 64u + joff));
            if (p01) h01 = *(const u16x8*)(h + ((unsigned)s01 * 64u + joff));
            if (p10) h10 = *(const u16x8*)(h + ((unsigned)s10 * 64u + joff));
            if (p11) h11 = *(const u16x8*)(h + ((unsigned)s11 * 64u + joff));
            if (p02) h02 = *(const u16x8*)(h + ((unsigned)s02 * 64u + joff));
            if (p03) h03 = *(const u16x8*)(h + ((unsigned)s03 * 64u + joff));
            if (p12) h12 = *(const u16x8*)(h + ((unsigned)s12 * 64u + joff));
            if (p13) h13 = *(const u16x8*)(h + ((unsigned)s13 * 64u + joff));

            float ex = 0.f;
            if (has) {
                float t = esv + edd;
                t = t > 0.f ? t : 0.2f * t;
                ex = __expf(t);
            }
            float sum = ex;
            #pragma unroll
            for (int off = 1; off < 32; off <<= 1) sum += __shfl_xor(sum, off);
            float a = ex / (sum + 1e-16f);

            float a00 = __shfl(a, i0), a01 = __shfl(a, i1);
            float a10 = __shfl(a, 32 + i0), a11 = __shfl(a, 32 + i1);
            float a02 = __shfl(a, i2), a03 = __shfl(a, i3);
            float a12 = __shfl(a, 32 + i2), a13 = __shfl(a, 32 + i3);

            float acc0[8], acc1[8];
            #pragma unroll
            for (int i = 0; i < 8; ++i) { acc0[i] = 0.f; acc1[i] = 0.f; }
            if (p00) fma8(acc0, a00, h00);
            if (p01) fma8(acc0, a01, h01);
            if (p10) fma8(acc1, a10, h10);
            if (p11) fma8(acc1, a11, h11);
            if (p02) fma8(acc0, a02, h02);
            if (p03) fma8(acc0, a03, h03);
            if (p12) fma8(acc1, a12, h12);
            if (p13) fma8(acc1, a13, h13);

            #pragma unroll
            for (int off = 8; off < 64; off <<= 1)
                #pragma unroll
                for (int i = 0; i < 8; ++i) {
                    acc0[i] += __shfl_xor(acc0[i], off);
                    acc1[i] += __shfl_xor(acc1[i], off);
                }

            if (g < 2) {
                int wnode = n0 + g;
                if (wnode < n) {
                    size_t base = (size_t)wnode * 64 + joff;
                    u16x8 o;
                    #pragma unroll
                    for (int i = 0; i < 8; ++i) {
                        float v = g ? acc1[i] : acc0[i];
                        o[i] = f2h_u(elu_f(v + bias[j * 8 + i]));
                    }
                    *(u16x8*)(xo + base) = o;
                    *(u16x8*)(&x_lds[wnode - blk16][joff]) = o;
                }
            }
        } else {
            // rare slow path: both nodes sequentially, 64-lane 3-pass scalar
            for (int k = 0; k < 2; ++k) {
                int nk = n0 + k;
                if (nk >= n) break;
                int start = __shfl(r0, k * 32);
                int end = start + __shfl(deg, k * 32);
                float edd = ed[nk];
                float m = -1e30f;
                for (int kk = start + lane; kk < end; kk += 64) {
                    float e = es[col[kk]] + edd;
                    e = e > 0.f ? e : 0.2f * e;
                    m = fmaxf(m, e);
                }
                #pragma unroll
                for (int off = 32; off; off >>= 1) m = fmaxf(m, __shfl_xor(m, off));
                float sum = 0.f;
                for (int kk = start + lane; kk < end; kk += 64) {
                    float e = es[col[kk]] + edd;
                    e = e > 0.f ? e : 0.2f * e;
                    sum += __expf(e - m);
                }
                #pragma unroll
                for (int off = 32; off; off >>= 1) sum += __shfl_xor(sum, off);
                float inv = 1.f / (sum + 1e-16f);
                float acc = 0.f;
                for (int kk = start; kk < end; ++kk) {
                    int s = col[kk];
                    float e = es[s] + edd;
                    e = e > 0.f ? e : 0.2f * e;
                    float al = __expf(e - m) * inv;
                    acc = fmaf(al, h2f_u(h[(size_t)s * 64 + lane]), acc);
                }
                size_t base = (size_t)nk * 64 + lane;
                unsigned short yv = f2h_u(elu_f(acc + bias[lane]));
                xo[base] = yv;
                x_lds[nk - blk16][lane] = yv;
            }
        }
    }

    __syncthreads();

    // ---- fused gemm for the next layer: waves 0-4, one col-tile each ----
    if (wvl < 5) {
        int c = lane & 15, quad = lane >> 4;
        const v8h a0 = *(const v8h*)(&x_lds[c][quad * 8]);
        const v8h a1 = *(const v8h*)(&x_lds[c][32 + quad * 8]);
        const v8h b0 = *(const v8h*)(Whf2 + (size_t)((2 * wvl) * 64 + lane) * 8);
        const v8h b1 = *(const v8h*)(Whf2 + (size_t)((2 * wvl + 1) * 64 + lane) * 8);
        v4f z = {0.f, 0.f, 0.f, 0.f};
        v4f acc = __builtin_amdgcn_mfma_f32_16x16x32_f16(a0, b0, z, 0, 0, 0);
        acc = __builtin_amdgcn_mfma_f32_16x16x32_f16(a1, b1, acc, 0, 0, 0);
        #pragma unroll
        for (int r = 0; r < 4; ++r) {
            int row = blk16 + quad * 4 + r;
            if (row < n) {
                if (wvl < 4) {
                    h2[(size_t)row * 64 + wvl * 16 + c] = f2h_u(acc[r]);
                } else {
                    if (c == 0) es2[row] = acc[r];
                    if (c == 1) ed2[row] = acc[r];
                }
            }
        }
    }
}

// Final layer: R11 agg verbatim (2 dst nodes/wave, one-shot), fuses the
// 4-layer mean into the output write.
__global__ __launch_bounds__(256) void agg_k(const unsigned short* __restrict__ h,
                                             const float* __restrict__ es,
                                             const float* __restrict__ ed, const int* __restrict__ rowptr,
                                             const int* __restrict__ col, const float* __restrict__ bias,
                                             unsigned short* __restrict__ xo,
                                             const unsigned short* __restrict__ x0,
                                             const unsigned short* __restrict__ x1,
                                             const unsigned short* __restrict__ x2,
                                             void* __restrict__ out, const int* __restrict__ flag,
                                             int write_out, int n) {
    int wv = (blockIdx.x * 256 + threadIdx.x) >> 6;
    int lane = threadIdx.x & 63;
    int n0 = wv * 2;
    if (n0 >= n) return;
    int half = lane >> 5, hl = lane & 31;
    int node = n0 + half;
    bool valid = node < n;
    int nodeC = valid ? node : n - 1;
    int r0 = rowptr[nodeC];
    int deg = valid ? (rowptr[nodeC + 1] - r0) : 0;

    if (__ballot(deg > 32) == 0) {
        float edd = valid ? ed[nodeC] : 0.f;
        bool has = hl < deg;
        int c = 0;
        float esv = 0.f;
        if (has) {
            c = col[r0 + hl];
            esv = es[(unsigned)c];              // issue scattered es load early
        }

        int deg0 = __shfl(deg, 0), deg1 = __shfl(deg, 32);
        int g = lane >> 3, j = lane & 7;        // 8 edge groups x 8 lanes x 16B
        unsigned joff = (unsigned)j * 8;
        int i0 = g, i1 = 8 + g, i2 = 16 + g, i3 = 24 + g;

        // ---- all 32 h-row loads issue here, before the softmax reduce ----
        int s00 = __shfl(c, i0), s01 = __shfl(c, i1);
        int s10 = __shfl(c, 32 + i0), s11 = __shfl(c, 32 + i1);
        int s02 = __shfl(c, i2), s03 = __shfl(c, i3);
        int s12 = __shfl(c, 32 + i2), s13 = __shfl(c, 32 + i3);
        bool p00 = i0 < deg0, p01 = i1 < deg0, p02 = i2 < deg0, p03 = i3 < deg0;
        bool p10 = i0 < deg1, p11 = i1 < deg1, p12 = i2 < deg1, p13 = i3 < deg1;
        u16x8 h00, h01, h10, h11, h02, h03, h12, h13;
        if (p00) h00 = *(const u16x8*)(h + ((unsigned)s00 * 64u + joff));
        if (p01) h01 = *(const u16x8*)(h + ((unsigned)s01 * 64u + joff));
        if (p10) h10 = *(const u16x8*)(h + ((unsigned)s10 * 64u + joff));
        if (p11) h11 = *(const u16x8*)(h + ((unsigned)s11 * 64u + joff));
        if (p02) h02 = *(const u16x8*)(h + ((unsigned)s02 * 64u + joff));
        if (p03) h03 = *(const u16x8*)(h + ((unsigned)s03 * 64u + joff));
        if (p12) h12 = *(const u16x8*)(h + ((unsigned)s12 * 64u + joff));
        if (p13) h13 = *(const u16x8*)(h + ((unsigned)s13 * 64u + joff));

        // ---- softmax (no max-sub; |e| small) ----
        float ex = 0.f;
        if (has) {
            float t = esv + edd;
            t = t > 0.f ? t : 0.2f * t;
            ex = __expf(t);
        }
        float sum = ex;
        #pragma unroll
        for (int off = 1; off < 32; off <<= 1) sum += __shfl_xor(sum, off);
        float a = ex / (sum + 1e-16f);

        float a00 = __shfl(a, i0), a01 = __shfl(a, i1);
        float a10 = __shfl(a, 32 + i0), a11 = __shfl(a, 32 + i1);
        float a02 = __shfl(a, i2), a03 = __shfl(a, i3);
        float a12 = __shfl(a, 32 + i2), a13 = __shfl(a, 32 + i3);

        float acc0[8], acc1[8];
        #pragma unroll
        for (int i = 0; i < 8; ++i) { acc0[i] = 0.f; acc1[i] = 0.f; }
        if (p00) fma8(acc0, a00, h00);
        if (p01) fma8(acc0, a01, h01);
        if (p10) fma8(acc1, a10, h10);
        if (p11) fma8(acc1, a11, h11);
        if (p02) fma8(acc0, a02, h02);
        if (p03) fma8(acc0, a03, h03);
        if (p12) fma8(acc1, a12, h12);
        if (p13) fma8(acc1, a13, h13);

        #pragma unroll
        for (int off = 8; off < 64; off <<= 1)
            #pragma unroll
            for (int i = 0; i < 8; ++i) {
                acc0[i] += __shfl_xor(acc0[i], off);
                acc1[i] += __shfl_xor(acc1[i], off);
            }

        // lanes 0-7 write node0, lanes 8-15 write node1
        if (g < 2) {
            int wnode = n0 + g;
            if (wnode < n) {
                size_t base = (size_t)wnode * 64 + joff;
                float y[8];
                #pragma unroll
                for (int i = 0; i < 8; ++i) {
                    float v = g ? acc1[i] : acc0[i];
                    y[i] = elu_f(v + bias[j * 8 + i]);
                }
                if (write_out) {
                    u16x8 a0v = *(const u16x8*)(x0 + base);
                    u16x8 a1v = *(const u16x8*)(x1 + base);
                    u16x8 a2v = *(const u16x8*)(x2 + base);
                    float v[8];
                    #pragma unroll
                    for (int i = 0; i < 8; ++i)
                        v[i] = (h2f_u(a0v[i]) + h2f_u(a1v[i]) + h2f_u(a2v[i]) + y[i]) * 0.25f;
                    if (*flag) {
                        u16x8 o;
                        #pragma unroll
                        for (int i = 0; i < 8; ++i) o[i] = f2bf(v[i]);
                        *(u16x8*)((unsigned short*)out + base) = o;
                    } else {
                        float4 o0 = make_float4(v[0], v[1], v[2], v[3]);
                        float4 o1 = make_float4(v[4], v[5], v[6], v[7]);
                        *(float4*)((float*)out + base) = o0;
                        *(float4*)((float*)out + base + 4) = o1;
                    }
                } else {
                    u16x8 o;
                    #pragma unroll
                    for (int i = 0; i < 8; ++i) o[i] = f2h_u(y[i]);
                    *(u16x8*)(xo + base) = o;
                }
            }
        }
    } else {
        // rare slow path: both nodes sequentially, 64-lane 3-pass scalar
        for (int k = 0; k < 2; ++k) {
            int nk = n0 + k;
            if (nk >= n) break;
            int start = __shfl(r0, k * 32);
            int end = start + __shfl(deg, k * 32);
            float edd = ed[nk];
            float m = -1e30f;
            for (int kk = start + lane; kk < end; kk += 64) {
                float e = es[col[kk]] + edd;
                e = e > 0.f ? e : 0.2f * e;
                m = fmaxf(m, e);
            }
            #pragma unroll
            for (int off = 32; off; off >>= 1) m = fmaxf(m, __shfl_xor(m, off));
            float sum = 0.f;
            for (int kk = start + lane; kk < end; kk += 64) {
                float e = es[col[kk]] + edd;
                e = e > 0.f ? e : 0.2f * e;
                sum += __expf(e - m);
            }
            #pragma unroll
            for (int off = 32; off; off >>= 1) sum += __shfl_xor(sum, off);
            float inv = 1.f / (sum + 1e-16f);
            float acc = 0.f;
            for (int kk = start; kk < end; ++kk) {
                int s = col[kk];
                float e = es[s] + edd;
                e = e > 0.f ? e : 0.2f * e;
                float al = __expf(e - m) * inv;
                acc = fmaf(al, h2f_u(h[(size_t)s * 64 + lane]), acc);
            }
            size_t base = (size_t)nk * 64 + lane;
            float y = elu_f(acc + bias[lane]);
            if (write_out) {
                float v = (h2f_u(x0[base]) + h2f_u(x1[base]) + h2f_u(x2[base]) + y) * 0.25f;
                if (*flag) ((unsigned short*)out)[base] = f2bf(v);
                else       ((float*)out)[base] = v;
            } else {
                xo[base] = f2h_u(y);
            }
        }
    }
}

// ---------------------------------------------------------------------------

extern "C" void kernel_launch(void* const* d_in, const int* in_sizes, int n_in,
                              void* d_out, int out_size, void* d_ws, size_t ws_size,
                              hipStream_t stream) {
    const int*  edge = (const int*)d_in[0];
    const void* emb  = d_in[1];
    const void* W    = d_in[2];
    const void* as_  = d_in[3];
    const void* ad_  = d_in[4];
    const void* b_   = d_in[5];

    const int E = in_sizes[0] / 2;
    const int N = in_sizes[1] / 64;
    const int L = in_sizes[2] / 4096;
    const int NB = (N + NPB - 1) >> BSHIFT;     // 196 scan blocks (<=256)
    const size_t N64 = (size_t)N * 64;

    char* p = (char*)d_ws;
    auto take = [&](size_t bytes) { char* r = p; p += (bytes + 255) & ~(size_t)255; return r; };
    unsigned short* x0 = (unsigned short*)take(N64 * 2);
    unsigned short* x1 = (unsigned short*)take(N64 * 2);
    unsigned short* x2 = (unsigned short*)take(N64 * 2);
    unsigned short* hA = (unsigned short*)take(N64 * 2);
    unsigned short* hB = (unsigned short*)take(N64 * 2);
    float* esA     = (float*)take((size_t)N * 4);
    float* edA     = (float*)take((size_t)N * 4);
    float* esB     = (float*)take((size_t)N * 4);
    float* edB     = (float*)take((size_t)N * 4);
    unsigned short* Whf = (unsigned short*)take((size_t)L * FRAG_STRIDE * 2);
    float* bf      = (float*)take((size_t)L * 64 * 4);
    int* rowptr    = (int*)take((size_t)(N + 1) * 4);
    int* col       = (int*)take((size_t)(E + N) * 4);
    int* degrank   = (int*)take((size_t)2 * N * 4);   // deg | rank (zeroed)
    int* deg       = degrank;
    int* rank      = degrank + N;
    int* bsum      = (int*)take(256 * 4);
    int* flag      = (int*)take(4);

    const int* srcp = edge;
    const int* dstp = edge + E;
    const int dchunk = (E + DCHUNK - 1) / DCHUNK;          // 782
    const int convblocks = (int)((N64 / 8 + 255) / 256);   // 8 elems / thread
    const int selfb = (N + 255) / 256;
    const int nblk = (N + 15) / 16;
    const int gemmblocks = (nblk + 3) / 4;                 // layer-0 gemm strips

    hipMemsetAsync(degrank, 0, (size_t)2 * N * 4, stream);
    conv_deg_k<<<dchunk + convblocks, 256, 0, stream>>>(emb, W, as_, ad_, b_, dstp, x0, Whf, bf,
                                                        deg, flag, (int)N64, L, E, dchunk);
    scan1_k<<<NB, 256, 0, stream>>>(deg, bsum, N);
    scan2_k<<<NB, 512, 0, stream>>>(deg, bsum, rowptr, N, E, NB);
    scat_gemm_k<<<dchunk + selfb + gemmblocks, 256, 0, stream>>>(srcp, dstp, rowptr, deg, rank,
                                                                 col, E, N, dchunk, selfb,
                                                                 x0, Whf, hA, esA, edA, nblk);

    const int strip_blocks = nblk;              // aggemm: 1 block per 16-node strip
    const int aggblocks = (N + 7) / 8;          // final agg: 2 nodes/wave, 4 waves/block

    // layer 0 agg + layer 1 gemm: gather hA -> x1, then x1 @ W1 -> hB/esB/edB
    aggemm_k<<<strip_blocks, 512, 0, stream>>>(hA, esA, edA, rowptr, col, bf,
                                               x1, Whf + (size_t)1 * FRAG_STRIDE,
                                               hB, esB, edB, N);
    // layer 1 agg + layer 2 gemm: gather hB -> x2, then x2 @ W2 -> hA/esA/edA
    aggemm_k<<<strip_blocks, 512, 0, stream>>>(hB, esB, edB, rowptr, col, bf + 64,
                                               x2, Whf + (size_t)2 * FRAG_STRIDE,
                                               hA, esA, edA, N);
    // layer 2 agg + fused 4-layer mean -> out
    agg_k<<<aggblocks, 256, 0, stream>>>(hA, esA, edA, rowptr, col, bf + 128,
                                         x1, x0, x1, x2, d_out, flag, 1, N);
}

// Round 8
// 325.012 us; speedup vs baseline: 1.2896x; 1.2896x over previous
//
#include <hip/hip_runtime.h>
#include <hip/hip_bf16.h>

// ---------------------------------------------------------------------------
// GAT forward: 3 layers, N=100k nodes, D=64, E=1.6M edges (+N self loops).
// CSR build atomic-free at global scope, pairs packed to u32 (src|local<<23):
//   conv_hist_k -> scanb_k -> scan_nb_k -> partition_k -> build_k
// Compute: gemm_k (layer 0, one-shot grid), aggemm_k (layers 0,1: R11 agg
// body + fused next-layer gemm from LDS-staged x rows; h/es/ed ping-pong
// buffered), agg_k (final layer, R11 verbatim, fuses the 4-layer mean).
// R17: revert to R13 exactly (best measured: 325.9us) + the one proven
// micro-fix since: aggemm x_lds padded [16][72] (breaks the 16-way MFMA-read
// bank conflict; R14/R15 verified -1.8us/dispatch). R16's direct-CSR scatter
// regressed 90us (write amplification: 4B scattered col writes = 64B sector
// each, 123MB WRITE_SIZE) -- the chunk-bucket partition's locally-dense
// writes were the point. Agg math untouched everywhere.
// ---------------------------------------------------------------------------

#define BSHIFT 9
#define NPB 512            // nodes per bucket
#define COL_CAP 10240      // LDS col image capacity per bucket (mean ~8700)
#define FRAG_STRIDE 5120   // 10 frags * 64 lanes * 8 halves per layer
#define CHUNK 8192         // edges per partition chunk

typedef _Float16 v8h __attribute__((ext_vector_type(8)));
typedef float v4f __attribute__((ext_vector_type(4)));
typedef unsigned short u16x8 __attribute__((ext_vector_type(8)));

__device__ inline float bf2f(unsigned short u) {
    return __uint_as_float(((unsigned int)u) << 16);
}
__device__ inline unsigned short f2bf(float v) {
    __hip_bfloat16 b = __float2bfloat16(v);
    return *reinterpret_cast<unsigned short*>(&b);
}
__device__ inline unsigned short f2h_u(float v) {
    return __builtin_bit_cast(unsigned short, (_Float16)v);
}
__device__ inline float h2f_u(unsigned short u) {
    return (float)__builtin_bit_cast(_Float16, u);
}

__device__ __forceinline__ void fma8(float* acc, float al, const u16x8& hv) {
    #pragma unroll
    for (int i = 0; i < 8; ++i) acc[i] = fmaf(al, h2f_u(hv[i]), acc[i]);
}

__device__ inline float load_in(const void* p, int i, int isbf) {
    if (isbf) return bf2f(((const unsigned short*)p)[i]);
    return ((const float*)p)[i];
}

// per-block dtype detection: all blocks sample the same first 1KB of emb ->
// deterministic identical answer (bf16 ~97% exponent-byte hits, f32 ~4%).
__device__ inline int detect_bf16_blk(const unsigned int* raw) {
    __shared__ int s4[4];
    unsigned int b = (raw[threadIdx.x] >> 8) & 0x7Fu;
    unsigned long long m = __ballot(b >= 0x3Bu && b <= 0x3Fu);
    int wv = threadIdx.x >> 6;
    if ((threadIdx.x & 63) == 0) s4[wv] = __popcll(m);
    __syncthreads();
    return (s4[0] + s4[1] + s4[2] + s4[3]) > 128 ? 1 : 0;
}

// blocks [0, nchunk): per-chunk bucket histogram (no global atomics)
// blocks [nchunk, ...): conversions (emb->x0 fp16, W->frags, bias), flag store
__global__ __launch_bounds__(256) void conv_hist_k(const void* emb, const void* W, const void* as_,
                                                   const void* ad_, const void* b_,
                                                   const int* __restrict__ dst,
                                                   unsigned short* x0, unsigned short* Whf,
                                                   float* bf, int* __restrict__ bh, int* flag,
                                                   int n, int L_, int E, int nchunk) {
    int blk = blockIdx.x;
    if (blk < nchunk) {
        __shared__ int h[256];
        h[threadIdx.x] = 0;
        __syncthreads();
        int cs = blk * CHUNK;
        int ce = min(cs + CHUNK, E);
        for (int i = cs + threadIdx.x; i < ce; i += 256)
            atomicAdd(&h[dst[i] >> BSHIFT], 1);
        __syncthreads();
        bh[threadIdx.x * nchunk + blk] = h[threadIdx.x];
        return;
    }
    int isbf = detect_bf16_blk((const unsigned int*)emb);
    int i = (blk - nchunk) * 256 + threadIdx.x;
    if (blk == nchunk && threadIdx.x == 0) *flag = isbf;
    // vectorized emb -> x0 fp16 conversion: 8 elems / thread (n % 8 == 0)
    long i8 = (long)i * 8;
    if (i8 < n) {
        u16x8 o;
        if (isbf) {
            u16x8 v = *(const u16x8*)((const unsigned short*)emb + i8);
            #pragma unroll
            for (int q = 0; q < 8; ++q) o[q] = f2h_u(bf2f(v[q]));
        } else {
            v4f f0 = *(const v4f*)((const float*)emb + i8);
            v4f f1 = *(const v4f*)((const float*)emb + i8 + 4);
            #pragma unroll
            for (int q = 0; q < 4; ++q) { o[q] = f2h_u(f0[q]); o[q + 4] = f2h_u(f1[q]); }
        }
        *(u16x8*)(x0 + i8) = o;
    }
    if (i < L_ * 4096) {
        int l = i >> 12, rem = i & 4095;
        int k = rem >> 6, c64 = rem & 63;
        int t = c64 >> 4, c = c64 & 15;
        int kf = k >> 5, quad = (k >> 3) & 3, j = k & 7;
        int f = t * 2 + kf, lane = quad * 16 + c;
        Whf[l * FRAG_STRIDE + (f * 64 + lane) * 8 + j] = f2h_u(load_in(W, i, isbf));
    }
    if (i < L_ * 1024) {                 // score tile: frags 8 (k<32), 9 (k>=32)
        int l = i >> 10, r = i & 1023;
        int kf = r >> 9, rr = r & 511;
        int lane = rr >> 3, j = rr & 7;
        int c = lane & 15, quad = lane >> 4;
        int k = kf * 32 + quad * 8 + j;
        float val = 0.f;
        if (c < 2) {
            const void* av = c ? ad_ : as_;
            float dot = 0.f;
            for (int cc = 0; cc < 64; ++cc)
                dot += load_in(W, l * 4096 + k * 64 + cc, isbf) * load_in(av, l * 64 + cc, isbf);
            val = dot;                   // (W @ a)[k]
        }
        Whf[l * FRAG_STRIDE + ((8 + kf) * 64 + lane) * 8 + j] = f2h_u(val);
    }
    if (i < L_ * 64) bf[i] = load_in(b_, i, isbf);
}

// ---- CSR build -------------------------------------------------------------

// block per bucket: exclusive scan of the chunk row (nchunk <= 512), total->ghist
__global__ __launch_bounds__(256) void scanb_k(int* __restrict__ bh, int* __restrict__ ghist,
                                               int nchunk) {
    __shared__ int s[256];
    int b = blockIdx.x, t = threadIdx.x;
    int i0 = 2 * t, i1 = 2 * t + 1;
    int v0 = (i0 < nchunk) ? bh[b * nchunk + i0] : 0;
    int v1 = (i1 < nchunk) ? bh[b * nchunk + i1] : 0;
    int p = v0 + v1;
    s[t] = p;
    __syncthreads();
    for (int off = 1; off < 256; off <<= 1) {
        int tv = (t >= off) ? s[t - off] : 0;
        __syncthreads();
        s[t] += tv;
        __syncthreads();
    }
    int excl = s[t] - p;
    if (i0 < nchunk) bh[b * nchunk + i0] = excl;
    if (i1 < nchunk) bh[b * nchunk + i1] = excl + v0;
    if (t == 255) ghist[b] = s[255];
}

// single block: cross-bucket exclusive scans (pairs sizes, col sizes)
__global__ __launch_bounds__(256) void scan_nb_k(const int* ghist, int* pairs_base, int* col_base,
                                                 int* rowptr, int N, int E, int NB) {
    __shared__ int s1[256], s2[256];
    int t = threadIdx.x;
    int hv = (t < NB) ? ghist[t] : 0;
    int npb = (t < NB) ? min(N - (t << BSHIFT), NPB) : 0;
    s1[t] = hv; s2[t] = hv + npb;
    __syncthreads();
    for (int off = 1; off < 256; off <<= 1) {
        int t1 = (t >= off) ? s1[t - off] : 0;
        int t2 = (t >= off) ? s2[t - off] : 0;
        __syncthreads();
        s1[t] += t1; s2[t] += t2;
        __syncthreads();
    }
    if (t < NB) {
        pairs_base[t] = s1[t] - hv;
        col_base[t]   = s2[t] - (hv + npb);
    }
    if (t == 0) rowptr[N] = E + N;
}

// one pass, zero global atomics: base from scanned histograms, rank via LDS.
// pair packed: src (23b) | local-dst (9b) << 23
__global__ __launch_bounds__(256) void partition_k(const int* __restrict__ src,
                                                   const int* __restrict__ dst,
                                                   const int* __restrict__ bh,
                                                   const int* __restrict__ pairs_base,
                                                   unsigned int* __restrict__ pairs,
                                                   int E, int NB, int nchunk) {
    __shared__ int base[256], rk[256];
    int t = threadIdx.x;
    base[t] = (t < NB) ? pairs_base[t] + bh[t * nchunk + blockIdx.x] : 0;
    rk[t] = 0;
    __syncthreads();
    int cs = blockIdx.x * CHUNK;
    int ce = min(cs + CHUNK, E);
    for (int i = cs + t; i < ce; i += 256) {
        int d = dst[i];
        int b = d >> BSHIFT;
        int r = atomicAdd(&rk[b], 1);
        pairs[base[b] + r] = (unsigned)src[i] | ((unsigned)(d & (NPB - 1)) << 23);
    }
}

__global__ __launch_bounds__(512) void build_k(const unsigned int* __restrict__ pairs,
                                               const int* __restrict__ ghist,
                                               const int* __restrict__ pairs_base,
                                               const int* __restrict__ col_base,
                                               int* __restrict__ rowptr, int* __restrict__ col,
                                               int N) {
    __shared__ int cnt[512], cnt2[512], sc[512], off[513];
    __shared__ int col_lds[COL_CAP];
    int b = blockIdx.x, t = threadIdx.x;
    int nloc = min(N - (b << BSHIFT), NPB);
    int ne = ghist[b], pb = pairs_base[b], cb = col_base[b];
    cnt[t] = 0; cnt2[t] = 0;
    __syncthreads();
    for (int i = t; i < ne; i += 512)
        atomicAdd(&cnt[pairs[pb + i] >> 23], 1);
    __syncthreads();
    int v = cnt[t] + (t < nloc ? 1 : 0);    // +1 self loop
    sc[t] = v;
    __syncthreads();
    for (int o = 1; o < 512; o <<= 1) {
        int tv = (t >= o) ? sc[t - o] : 0;
        __syncthreads();
        sc[t] += tv;
        __syncthreads();
    }
    off[t + 1] = sc[t];
    if (t == 0) off[0] = 0;
    __syncthreads();
    if (t < nloc) rowptr[(b << BSHIFT) + t] = cb + off[t];
    int total = off[nloc];                   // == ne + nloc
    bool fit = (total <= COL_CAP);
    for (int i = t; i < ne; i += 512) {
        unsigned int p = pairs[pb + i];
        int loc = p >> 23;
        int pos = off[loc] + atomicAdd(&cnt2[loc], 1);
        int sv = (int)(p & 0x7FFFFFu);
        if (fit) col_lds[pos] = sv;
        else     col[cb + pos] = sv;         // overflow fallback
    }
    if (t < nloc) {
        int pos = off[t + 1] - 1;            // self-loop slot
        int sv = (b << BSHIFT) + t;
        if (fit) col_lds[pos] = sv;
        else     col[cb + pos] = sv;
    }
    __syncthreads();
    if (fit)
        for (int i = t; i < total; i += 512) col[cb + i] = col_lds[i];
}

// ---- per-layer compute -----------------------------------------------------

// MFMA GEMM, 16-node strip per wave, 5 col-tiles (4 = h, 1 = scores).
// A: row=lane&15, k=(lane>>4)*8+j.  C: col=lane&15, row=(lane>>4)*4+reg.
// Launched one-shot (1 strip per wave).
__global__ __launch_bounds__(256) void gemm_k(const unsigned short* __restrict__ x,
                                              const unsigned short* __restrict__ Whf,
                                              unsigned short* __restrict__ h,
                                              float* __restrict__ es, float* __restrict__ ed,
                                              int n, int nblk, int nwaves) {
    int lane = threadIdx.x & 63;
    int gwave = (blockIdx.x * 256 + threadIdx.x) >> 6;
    int c = lane & 15, quad = lane >> 4;

    v8h bfr[10];
    #pragma unroll
    for (int f = 0; f < 10; ++f)
        bfr[f] = *(const v8h*)(Whf + (size_t)(f * 64 + lane) * 8);

    v4f z = {0.f, 0.f, 0.f, 0.f};
    for (int nb = gwave; nb < nblk; nb += nwaves) {
        int base = nb * 16;
        int m = base + c; if (m >= n) m = n - 1;
        const v8h a0 = *(const v8h*)(x + (size_t)m * 64 + quad * 8);
        const v8h a1 = *(const v8h*)(x + (size_t)m * 64 + 32 + quad * 8);
        v4f acc[5];
        #pragma unroll
        for (int t = 0; t < 5; ++t) {
            acc[t] = __builtin_amdgcn_mfma_f32_16x16x32_f16(a0, bfr[2 * t], z, 0, 0, 0);
            acc[t] = __builtin_amdgcn_mfma_f32_16x16x32_f16(a1, bfr[2 * t + 1], acc[t], 0, 0, 0);
        }
        #pragma unroll
        for (int r = 0; r < 4; ++r) {
            int row = base + quad * 4 + r;
            if (row < n) {
                #pragma unroll
                for (int t = 0; t < 4; ++t)
                    h[(size_t)row * 64 + t * 16 + c] = f2h_u(acc[t][r]);
                if (c == 0) es[row] = acc[4][r];
                if (c == 1) ed[row] = acc[4][r];
            }
        }
    }
}

__device__ inline float elu_f(float v) { return v > 0.f ? v : (__expf(v) - 1.f); }

// Fused agg + next-layer gemm. Block = 8 waves = 16 nodes = 1 gemm strip.
// Agg body is R11 verbatim (2 dst nodes/wave, all-32 h loads before softmax,
// same fma order -> bit-identical). Output x rows stashed in LDS (padded
// [16][72] to break the 16-way MFMA-read bank conflict); after the block
// barrier, waves 0-4 each compute one 16x16 col-tile of the NEXT layer's h
// (tiles 0-3) / es,ed (tile 4) via the same MFMA sequence gemm_k uses ->
// bit-identical h/es/ed.
__global__ __launch_bounds__(512) void aggemm_k(const unsigned short* __restrict__ h,
                                                const float* __restrict__ es,
                                                const float* __restrict__ ed,
                                                const int* __restrict__ rowptr,
                                                const int* __restrict__ col,
                                                const float* __restrict__ bias,
                                                unsigned short* __restrict__ xo,
                                                const unsigned short* __restrict__ Whf2,
                                                unsigned short* __restrict__ h2,
                                                float* __restrict__ es2,
                                                float* __restrict__ ed2,
                                                int n) {
    __shared__ unsigned short x_lds[16][72];   // padded: 144B row stride
    int wvl = threadIdx.x >> 6;          // 0..7
    int lane = threadIdx.x & 63;
    int blk16 = blockIdx.x * 16;
    int n0 = blk16 + wvl * 2;

    if (n0 < n) {
        int half = lane >> 5, hl = lane & 31;
        int node = n0 + half;
        bool valid = node < n;
        int nodeC = valid ? node : n - 1;
        int r0 = rowptr[nodeC];
        int deg = valid ? (rowptr[nodeC + 1] - r0) : 0;

        if (__ballot(deg > 32) == 0) {
            float edd = valid ? ed[nodeC] : 0.f;
            bool has = hl < deg;
            int c = 0;
            float esv = 0.f;
            if (has) {
                c = col[r0 + hl];
                esv = es[(unsigned)c];
            }

            int deg0 = __shfl(deg, 0), deg1 = __shfl(deg, 32);
            int g = lane >> 3, j = lane & 7;
            unsigned joff = (unsigned)j * 8;
            int i0 = g, i1 = 8 + g, i2 = 16 + g, i3 = 24 + g;

            int s00 = __shfl(c, i0), s01 = __shfl(c, i1);
            int s10 = __shfl(c, 32 + i0), s11 = __shfl(c, 32 + i1);
            int s02 = __shfl(c, i2), s03 = __shfl(c, i3);
            int s12 = __shfl(c, 32 + i2), s13 = __shfl(c, 32 + i3);
            bool p00 = i0 < deg0, p01 = i1 < deg0, p02 = i2 < deg0, p03 = i3 < deg0;
            bool p10 = i0 < deg1, p11 = i1 < deg1, p12 = i2 < deg1, p13 = i3 < deg1;
            u16x8 h00, h01, h10, h11, h02, h03, h12, h13;
            if (p00) h00 = *(const u16x8*)(h + ((unsigned)s00 * 64u + joff));
            if (p01) h01 = *(const u16x8*)(h + ((unsigned)s01 * 64u + joff));
            if (p10) h10 = *(const u16x8*)(h + ((unsigned)s10 * 64u + joff));
            if (p11) h11 = *(const u16x8*)(h + ((unsigned)s11 * 64u + joff));
            if (p02) h02 = *(const u16x8*)(h + ((unsigned)s02 * 64u + joff));
            if (p03) h03 = *(const u16x8*)(h + ((unsigned)s03 * 64u + joff));
            if (p12) h12 = *(const u16x8*)(h + ((unsigned)s12 * 64u + joff));
            if (p13) h13 = *(const u16x8*)(h + ((unsigned)s13 * 64u + joff));

            float ex = 0.f;
            if (has) {
                float t = esv + edd;
                t = t > 0.f ? t : 0.2f * t;
                ex = __expf(t);
            }
            float sum = ex;
            #pragma unroll
            for (int off = 1; off < 32; off <<= 1) sum += __shfl_xor(sum, off);
            float a = ex / (sum + 1e-16f);

            float a00 = __shfl(a, i0), a01 = __shfl(a, i1);
            float a10 = __shfl(a, 32 + i0), a11 = __shfl(a, 32 + i1);
            float a02 = __shfl(a, i2), a03 = __shfl(a, i3);
            float a12 = __shfl(a, 32 + i2), a13 = __shfl(a, 32 + i3);

            float acc0[8], acc1[8];
            #pragma unroll
            for (int i = 0; i < 8; ++i) { acc0[i] = 0.f; acc1[i] = 0.f; }
            if (p00) fma8(acc0, a00, h00);
            if (p01) fma8(acc0, a01, h01);
            if (p10) fma8(acc1, a10, h10);
            if (p11) fma8(acc1, a11, h11);
            if (p02) fma8(acc0, a02, h02);
            if (p03) fma8(acc0, a03, h03);
            if (p12) fma8(acc1, a12, h12);
            if (p13) fma8(acc1, a13, h13);

            #pragma unroll
            for (int off = 8; off < 64; off <<= 1)
                #pragma unroll
                for (int i = 0; i < 8; ++i) {
                    acc0[i] += __shfl_xor(acc0[i], off);
                    acc1[i] += __shfl_xor(acc1[i], off);
                }

            if (g < 2) {
                int wnode = n0 + g;
                if (wnode < n) {
                    size_t base = (size_t)wnode * 64 + joff;
                    u16x8 o;
                    #pragma unroll
                    for (int i = 0; i < 8; ++i) {
                        float v = g ? acc1[i] : acc0[i];
                        o[i] = f2h_u(elu_f(v + bias[j * 8 + i]));
                    }
                    *(u16x8*)(xo + base) = o;
                    *(u16x8*)(&x_lds[wnode - blk16][joff]) = o;
                }
            }
        } else {
            // rare slow path: both nodes sequentially, 64-lane 3-pass scalar
            for (int k = 0; k < 2; ++k) {
                int nk = n0 + k;
                if (nk >= n) break;
                int start = __shfl(r0, k * 32);
                int end = start + __shfl(deg, k * 32);
                float edd = ed[nk];
                float m = -1e30f;
                for (int kk = start + lane; kk < end; kk += 64) {
                    float e = es[col[kk]] + edd;
                    e = e > 0.f ? e : 0.2f * e;
                    m = fmaxf(m, e);
                }
                #pragma unroll
                for (int off = 32; off; off >>= 1) m = fmaxf(m, __shfl_xor(m, off));
                float sum = 0.f;
                for (int kk = start + lane; kk < end; kk += 64) {
                    float e = es[col[kk]] + edd;
                    e = e > 0.f ? e : 0.2f * e;
                    sum += __expf(e - m);
                }
                #pragma unroll
                for (int off = 32; off; off >>= 1) sum += __shfl_xor(sum, off);
                float inv = 1.f / (sum + 1e-16f);
                float acc = 0.f;
                for (int kk = start; kk < end; ++kk) {
                    int s = col[kk];
                    float e = es[s] + edd;
                    e = e > 0.f ? e : 0.2f * e;
                    float al = __expf(e - m) * inv;
                    acc = fmaf(al, h2f_u(h[(size_t)s * 64 + lane]), acc);
                }
                size_t base = (size_t)nk * 64 + lane;
                unsigned short yv = f2h_u(elu_f(acc + bias[lane]));
                xo[base] = yv;
                x_lds[nk - blk16][lane] = yv;
            }
        }
    }

    __syncthreads();

    // ---- fused gemm for the next layer: waves 0-4, one col-tile each ----
    if (wvl < 5) {
        int c = lane & 15, quad = lane >> 4;
        const v8h a0 = *(const v8h*)(&x_lds[c][quad * 8]);
        const v8h a1 = *(const v8h*)(&x_lds[c][32 + quad * 8]);
        const v8h b0 = *(const v8h*)(Whf2 + (size_t)((2 * wvl) * 64 + lane) * 8);
        const v8h b1 = *(const v8h*)(Whf2 + (size_t)((2 * wvl + 1) * 64 + lane) * 8);
        v4f z = {0.f, 0.f, 0.f, 0.f};
        v4f acc = __builtin_amdgcn_mfma_f32_16x16x32_f16(a0, b0, z, 0, 0, 0);
        acc = __builtin_amdgcn_mfma_f32_16x16x32_f16(a1, b1, acc, 0, 0, 0);
        #pragma unroll
        for (int r = 0; r < 4; ++r) {
            int row = blk16 + quad * 4 + r;
            if (row < n) {
                if (wvl < 4) {
                    h2[(size_t)row * 64 + wvl * 16 + c] = f2h_u(acc[r]);
                } else {
                    if (c == 0) es2[row] = acc[r];
                    if (c == 1) ed2[row] = acc[r];
                }
            }
        }
    }
}

// Final layer: R11 agg verbatim (2 dst nodes/wave, one-shot), fuses the
// 4-layer mean into the output write.
__global__ __launch_bounds__(256) void agg_k(const unsigned short* __restrict__ h,
                                             const float* __restrict__ es,
                                             const float* __restrict__ ed, const int* __restrict__ rowptr,
                                             const int* __restrict__ col, const float* __restrict__ bias,
                                             unsigned short* __restrict__ xo,
                                             const unsigned short* __restrict__ x0,
                                             const unsigned short* __restrict__ x1,
                                             const unsigned short* __restrict__ x2,
                                             void* __restrict__ out, const int* __restrict__ flag,
                                             int write_out, int n) {
    int wv = (blockIdx.x * 256 + threadIdx.x) >> 6;
    int lane = threadIdx.x & 63;
    int n0 = wv * 2;
    if (n0 >= n) return;
    int half = lane >> 5, hl = lane & 31;
    int node = n0 + half;
    bool valid = node < n;
    int nodeC = valid ? node : n - 1;
    int r0 = rowptr[nodeC];
    int deg = valid ? (rowptr[nodeC + 1] - r0) : 0;

    if (__ballot(deg > 32) == 0) {
        float edd = valid ? ed[nodeC] : 0.f;
        bool has = hl < deg;
        int c = 0;
        float esv = 0.f;
        if (has) {
            c = col[r0 + hl];
            esv = es[(unsigned)c];              // issue scattered es load early
        }

        int deg0 = __shfl(deg, 0), deg1 = __shfl(deg, 32);
        int g = lane >> 3, j = lane & 7;        // 8 edge groups x 8 lanes x 16B
        unsigned joff = (unsigned)j * 8;
        int i0 = g, i1 = 8 + g, i2 = 16 + g, i3 = 24 + g;

        // ---- all 32 h-row loads issue here, before the softmax reduce ----
        int s00 = __shfl(c, i0), s01 = __shfl(c, i1);
        int s10 = __shfl(c, 32 + i0), s11 = __shfl(c, 32 + i1);
        int s02 = __shfl(c, i2), s03 = __shfl(c, i3);
        int s12 = __shfl(c, 32 + i2), s13 = __shfl(c, 32 + i3);
        bool p00 = i0 < deg0, p01 = i1 < deg0, p02 = i2 < deg0, p03 = i3 < deg0;
        bool p10 = i0 < deg1, p11 = i1 < deg1, p12 = i2 < deg1, p13 = i3 < deg1;
        u16x8 h00, h01, h10, h11, h02, h03, h12, h13;
        if (p00) h00 = *(const u16x8*)(h + ((unsigned)s00 * 64u + joff));
        if (p01) h01 = *(const u16x8*)(h + ((unsigned)s01 * 64u + joff));
        if (p10) h10 = *(const u16x8*)(h + ((unsigned)s10 * 64u + joff));
        if (p11) h11 = *(const u16x8*)(h + ((unsigned)s11 * 64u + joff));
        if (p02) h02 = *(const u16x8*)(h + ((unsigned)s02 * 64u + joff));
        if (p03) h03 = *(const u16x8*)(h + ((unsigned)s03 * 64u + joff));
        if (p12) h12 = *(const u16x8*)(h + ((unsigned)s12 * 64u + joff));
        if (p13) h13 = *(const u16x8*)(h + ((unsigned)s13 * 64u + joff));

        // ---- softmax (no max-sub; |e| small) ----
        float ex = 0.f;
        if (has) {
            float t = esv + edd;
            t = t > 0.f ? t : 0.2f * t;
            ex = __expf(t);
        }
        float sum = ex;
        #pragma unroll
        for (int off = 1; off < 32; off <<= 1) sum += __shfl_xor(sum, off);
        float a = ex / (sum + 1e-16f);

        float a00 = __shfl(a, i0), a01 = __shfl(a, i1);
        float a10 = __shfl(a, 32 + i0), a11 = __shfl(a, 32 + i1);
        float a02 = __shfl(a, i2), a03 = __shfl(a, i3);
        float a12 = __shfl(a, 32 + i2), a13 = __shfl(a, 32 + i3);

        float acc0[8], acc1[8];
        #pragma unroll
        for (int i = 0; i < 8; ++i) { acc0[i] = 0.f; acc1[i] = 0.f; }
        if (p00) fma8(acc0, a00, h00);
        if (p01) fma8(acc0, a01, h01);
        if (p10) fma8(acc1, a10, h10);
        if (p11) fma8(acc1, a11, h11);
        if (p02) fma8(acc0, a02, h02);
        if (p03) fma8(acc0, a03, h03);
        if (p12) fma8(acc1, a12, h12);
        if (p13) fma8(acc1, a13, h13);

        #pragma unroll
        for (int off = 8; off < 64; off <<= 1)
            #pragma unroll
            for (int i = 0; i < 8; ++i) {
                acc0[i] += __shfl_xor(acc0[i], off);
                acc1[i] += __shfl_xor(acc1[i], off);
            }

        // lanes 0-7 write node0, lanes 8-15 write node1
        if (g < 2) {
            int wnode = n0 + g;
            if (wnode < n) {
                size_t base = (size_t)wnode * 64 + joff;
                float y[8];
                #pragma unroll
                for (int i = 0; i < 8; ++i) {
                    float v = g ? acc1[i] : acc0[i];
                    y[i] = elu_f(v + bias[j * 8 + i]);
                }
                if (write_out) {
                    u16x8 a0v = *(const u16x8*)(x0 + base);
                    u16x8 a1v = *(const u16x8*)(x1 + base);
                    u16x8 a2v = *(const u16x8*)(x2 + base);
                    float v[8];
                    #pragma unroll
                    for (int i = 0; i < 8; ++i)
                        v[i] = (h2f_u(a0v[i]) + h2f_u(a1v[i]) + h2f_u(a2v[i]) + y[i]) * 0.25f;
                    if (*flag) {
                        u16x8 o;
                        #pragma unroll
                        for (int i = 0; i < 8; ++i) o[i] = f2bf(v[i]);
                        *(u16x8*)((unsigned short*)out + base) = o;
                    } else {
                        float4 o0 = make_float4(v[0], v[1], v[2], v[3]);
                        float4 o1 = make_float4(v[4], v[5], v[6], v[7]);
                        *(float4*)((float*)out + base) = o0;
                        *(float4*)((float*)out + base + 4) = o1;
                    }
                } else {
                    u16x8 o;
                    #pragma unroll
                    for (int i = 0; i < 8; ++i) o[i] = f2h_u(y[i]);
                    *(u16x8*)(xo + base) = o;
                }
            }
        }
    } else {
        // rare slow path: both nodes sequentially, 64-lane 3-pass scalar
        for (int k = 0; k < 2; ++k) {
            int nk = n0 + k;
            if (nk >= n) break;
            int start = __shfl(r0, k * 32);
            int end = start + __shfl(deg, k * 32);
            float edd = ed[nk];
            float m = -1e30f;
            for (int kk = start + lane; kk < end; kk += 64) {
                float e = es[col[kk]] + edd;
                e = e > 0.f ? e : 0.2f * e;
                m = fmaxf(m, e);
            }
            #pragma unroll
            for (int off = 32; off; off >>= 1) m = fmaxf(m, __shfl_xor(m, off));
            float sum = 0.f;
            for (int kk = start + lane; kk < end; kk += 64) {
                float e = es[col[kk]] + edd;
                e = e > 0.f ? e : 0.2f * e;
                sum += __expf(e - m);
            }
            #pragma unroll
            for (int off = 32; off; off >>= 1) sum += __shfl_xor(sum, off);
            float inv = 1.f / (sum + 1e-16f);
            float acc = 0.f;
            for (int kk = start; kk < end; ++kk) {
                int s = col[kk];
                float e = es[s] + edd;
                e = e > 0.f ? e : 0.2f * e;
                float al = __expf(e - m) * inv;
                acc = fmaf(al, h2f_u(h[(size_t)s * 64 + lane]), acc);
            }
            size_t base = (size_t)nk * 64 + lane;
            float y = elu_f(acc + bias[lane]);
            if (write_out) {
                float v = (h2f_u(x0[base]) + h2f_u(x1[base]) + h2f_u(x2[base]) + y) * 0.25f;
                if (*flag) ((unsigned short*)out)[base] = f2bf(v);
                else       ((float*)out)[base] = v;
            } else {
                xo[base] = f2h_u(y);
            }
        }
    }
}

// ---------------------------------------------------------------------------

extern "C" void kernel_launch(void* const* d_in, const int* in_sizes, int n_in,
                              void* d_out, int out_size, void* d_ws, size_t ws_size,
                              hipStream_t stream) {
    const int*  edge = (const int*)d_in[0];
    const void* emb  = d_in[1];
    const void* W    = d_in[2];
    const void* as_  = d_in[3];
    const void* ad_  = d_in[4];
    const void* b_   = d_in[5];

    const int E = in_sizes[0] / 2;
    const int N = in_sizes[1] / 64;
    const int L = in_sizes[2] / 4096;
    const int NB = (N + NPB - 1) >> BSHIFT;     // 196 buckets (<=256)
    const int nchunk = (E + CHUNK - 1) / CHUNK; // 196 (<=512)
    const size_t N64 = (size_t)N * 64;

    char* p = (char*)d_ws;
    auto take = [&](size_t bytes) { char* r = p; p += (bytes + 255) & ~(size_t)255; return r; };
    unsigned short* x0 = (unsigned short*)take(N64 * 2);
    unsigned short* x1 = (unsigned short*)take(N64 * 2);
    unsigned short* hA = (unsigned short*)take(N64 * 2);
    unsigned short* hB = (unsigned short*)take(N64 * 2);
    unsigned int* pairs = (unsigned int*)take((size_t)E * 4 > N64 * 2 ? (size_t)E * 4 : N64 * 2);
    unsigned short* x2 = (unsigned short*)pairs;   // pairs dead after build_k
    float* esA     = (float*)take((size_t)N * 4);
    float* edA     = (float*)take((size_t)N * 4);
    float* esB     = (float*)take((size_t)N * 4);
    float* edB     = (float*)take((size_t)N * 4);
    unsigned short* Whf = (unsigned short*)take((size_t)L * FRAG_STRIDE * 2);
    float* bf      = (float*)take((size_t)L * 64 * 4);
    int* rowptr    = (int*)take((size_t)(N + 1) * 4);
    int* col       = (int*)take((size_t)(E + N) * 4);
    int* bh        = (int*)take((size_t)256 * 512 * 4);
    int* ghist     = (int*)take(256 * 4);
    int* pairs_base= (int*)take(256 * 4);
    int* col_base  = (int*)take(256 * 4);
    int* flag      = (int*)take(4);

    const int* srcp = edge;
    const int* dstp = edge + E;
    const int convblocks = (int)((N64 / 8 + 255) / 256);   // 8 elems / thread

    conv_hist_k<<<nchunk + convblocks, 256, 0, stream>>>(emb, W, as_, ad_, b_, dstp, x0, Whf, bf,
                                                         bh, flag, (int)N64, L, E, nchunk);
    scanb_k<<<NB, 256, 0, stream>>>(bh, ghist, nchunk);
    scan_nb_k<<<1, 256, 0, stream>>>(ghist, pairs_base, col_base, rowptr, N, E, NB);
    partition_k<<<nchunk, 256, 0, stream>>>(srcp, dstp, bh, pairs_base, pairs, E, NB, nchunk);
    build_k<<<NB, 512, 0, stream>>>(pairs, ghist, pairs_base, col_base, rowptr, col, N);

    const int nblk = (N + 15) / 16;
    const int ggrid = (nblk + 3) / 4;           // one-shot: 1 strip per wave
    const int strip_blocks = nblk;              // aggemm: 1 block per 16-node strip
    const int aggblocks = (N + 7) / 8;          // final agg: 2 nodes/wave, 4 waves/block

    // layer 0 gemm: x0 -> hA/esA/edA
    gemm_k<<<ggrid, 256, 0, stream>>>(x0, Whf, hA, esA, edA, N, nblk, ggrid * 4);
    // layer 0 agg + layer 1 gemm: gather hA -> x1, then x1 @ W1 -> hB/esB/edB
    aggemm_k<<<strip_blocks, 512, 0, stream>>>(hA, esA, edA, rowptr, col, bf,
                                               x1, Whf + (size_t)1 * FRAG_STRIDE,
                                               hB, esB, edB, N);
    // layer 1 agg + layer 2 gemm: gather hB -> x2, then x2 @ W2 -> hA/esA/edA
    aggemm_k<<<strip_blocks, 512, 0, stream>>>(hB, esB, edB, rowptr, col, bf + 64,
                                               x2, Whf + (size_t)2 * FRAG_STRIDE,
                                               hA, esA, edA, N);
    // layer 2 agg + fused 4-layer mean -> out
    agg_k<<<aggblocks, 256, 0, stream>>>(hA, esA, edA, rowptr, col, bf + 128,
                                         x1, x0, x1, x2, d_out, flag, 1, N);
}